// Round 2
// baseline (522.319 us; speedup 1.0000x reference)
//
#include <hip/hip_runtime.h>
#include <math.h>

#define N_NODES 200000
#define BGRAPH  1024
#define HDIM    256
#define ODIM    128
#define TSTEPS  2

#define ACT_NONE 0
#define ACT_ELU  1

// K0: v = W @ att_src, u = W @ att_dst   (W row-major [H,H]; xs = x@W => v_i = sum_j W[i,j]att_src[j])
__global__ void k_vectors(const float* __restrict__ W, const float* __restrict__ att_src,
                          const float* __restrict__ att_dst, float* __restrict__ v,
                          float* __restrict__ u) {
    int i = threadIdx.x;
    float sv = 0.f, su = 0.f;
    for (int j = 0; j < HDIM; ++j) {
        float w = W[i * HDIM + j];
        sv += w * att_src[j];
        su += w * att_dst[j];
    }
    v[i] = sv; u[i] = su;
}

// K1: segment boundaries via binary search (batch is sorted ascending)
__global__ void k_bounds(const int* __restrict__ batch, int* __restrict__ seg) {
    int b = blockIdx.x * blockDim.x + threadIdx.x;
    if (b > BGRAPH) return;
    if (b == BGRAPH) { seg[b] = N_NODES; return; }
    int lo = 0, hi = N_NODES;
    while (lo < hi) { int mid = (lo + hi) >> 1; if (batch[mid] < b) lo = mid + 1; else hi = mid; }
    seg[b] = lo;
}

// K2: fused pool (out_0) + s_i = x_i . v.  One block per graph (contiguous segment), wave-per-node.
__global__ __launch_bounds__(256) void k_passA(const float* __restrict__ x,
        const int* __restrict__ seg, const float* __restrict__ v,
        float* __restrict__ s, float* __restrict__ stt) {
    int b = blockIdx.x;
    int lo = seg[b], hi = seg[b + 1];
    int t = threadIdx.x, wave = t >> 6, lane = t & 63;
    float v0 = v[4 * lane + 0], v1 = v[4 * lane + 1], v2 = v[4 * lane + 2], v3 = v[4 * lane + 3];
    float p0 = 0.f, p1 = 0.f, p2 = 0.f, p3 = 0.f;
    for (int i = lo + wave; i < hi; i += 4) {
        const float4 r = *(const float4*)(x + (size_t)i * HDIM + 4 * lane);
        p0 += r.x; p1 += r.y; p2 += r.z; p3 += r.w;
        float part = r.x * v0 + r.y * v1 + r.z * v2 + r.w * v3;
        #pragma unroll
        for (int off = 32; off > 0; off >>= 1) part += __shfl_down(part, off, 64);
        if (lane == 0) s[i] = part;
    }
    __shared__ float comb[4][HDIM];
    comb[wave][4 * lane + 0] = p0; comb[wave][4 * lane + 1] = p1;
    comb[wave][4 * lane + 2] = p2; comb[wave][4 * lane + 3] = p3;
    __syncthreads();
    stt[(size_t)b * HDIM + t] = comb[0][t] + comb[1][t] + comb[2][t] + comb[3][t];
}

// K_iter: per graph: d = out_b.u ; softmax over segment scores; aggx_b = sum_i alpha_i * x_i
__global__ __launch_bounds__(256) void k_iter(const float* __restrict__ x,
        const int* __restrict__ seg, const float* __restrict__ s,
        const float* __restrict__ u, const float* __restrict__ stt,
        float* __restrict__ aggx) {
    int b = blockIdx.x, t = threadIdx.x;
    int lo = seg[b], hi = seg[b + 1];
    __shared__ float red[256];
    // d = stt[b] . u
    red[t] = stt[(size_t)b * HDIM + t] * u[t];
    __syncthreads();
    for (int st = 128; st > 0; st >>= 1) { if (t < st) red[t] += red[t + st]; __syncthreads(); }
    float d = red[0];
    __syncthreads();
    // emax
    float m = -3.402823466e38f;
    for (int i = lo + t; i < hi; i += 256) {
        float e = s[i] + d; e = e > 0.f ? e : 0.01f * e;
        m = fmaxf(m, e);
    }
    red[t] = m; __syncthreads();
    for (int st = 128; st > 0; st >>= 1) { if (t < st) red[t] = fmaxf(red[t], red[t + st]); __syncthreads(); }
    float M = red[0];
    __syncthreads();
    // denom
    float sm = 0.f;
    for (int i = lo + t; i < hi; i += 256) {
        float e = s[i] + d; e = e > 0.f ? e : 0.01f * e;
        sm += __expf(e - M);
    }
    red[t] = sm; __syncthreads();
    for (int st = 128; st > 0; st >>= 1) { if (t < st) red[t] += red[t + st]; __syncthreads(); }
    float inv = (hi > lo) ? 1.0f / red[0] : 0.f;
    __syncthreads();
    // weighted aggregation, wave-per-node
    int wave = t >> 6, lane = t & 63;
    float a0 = 0.f, a1 = 0.f, a2 = 0.f, a3 = 0.f;
    for (int i = lo + wave; i < hi; i += 4) {
        float e = s[i] + d; e = e > 0.f ? e : 0.01f * e;
        float alpha = __expf(e - M) * inv;
        const float4 r = *(const float4*)(x + (size_t)i * HDIM + 4 * lane);
        a0 += alpha * r.x; a1 += alpha * r.y; a2 += alpha * r.z; a3 += alpha * r.w;
    }
    __shared__ float comb[4][HDIM];
    comb[wave][4 * lane + 0] = a0; comb[wave][4 * lane + 1] = a1;
    comb[wave][4 * lane + 2] = a2; comb[wave][4 * lane + 3] = a3;
    __syncthreads();
    aggx[(size_t)b * HDIM + t] = comb[0][t] + comb[1][t] + comb[2][t] + comb[3][t];
}

// Generic small GEMM: C[M,N] = act(A[M,K] * B + bias), all f32.
//   BT=false: B row-major [K,N]; BT=true: B row-major [N,K] (C = A*B^T)
// 64x64 tile, 256 threads, 4x4 microtile, BK=16.
template<bool BT, int ACT>
__global__ __launch_bounds__(256) void k_gemm(const float* __restrict__ A,
        const float* __restrict__ B, const float* __restrict__ bias,
        float* __restrict__ C, int M, int N, int K) {
    __shared__ __align__(16) float As[16][64];
    __shared__ __align__(16) float Bs[16][64];
    int tx = threadIdx.x & 15, ty = threadIdx.x >> 4;
    int m0 = blockIdx.x * 64, n0 = blockIdx.y * 64;
    float acc[4][4] = {};
    for (int k0 = 0; k0 < K; k0 += 16) {
        {
            int r = threadIdx.x >> 2;
            int kk = (threadIdx.x & 3) << 2;
            float4 av = *(const float4*)(A + (size_t)(m0 + r) * K + k0 + kk);
            As[kk + 0][r] = av.x; As[kk + 1][r] = av.y;
            As[kk + 2][r] = av.z; As[kk + 3][r] = av.w;
        }
        if (BT) {
            int r = threadIdx.x >> 2;
            int kk = (threadIdx.x & 3) << 2;
            float4 bv = *(const float4*)(B + (size_t)(n0 + r) * K + k0 + kk);
            Bs[kk + 0][r] = bv.x; Bs[kk + 1][r] = bv.y;
            Bs[kk + 2][r] = bv.z; Bs[kk + 3][r] = bv.w;
        } else {
            int kk = threadIdx.x >> 4;
            int nn = (threadIdx.x & 15) << 2;
            float4 bv = *(const float4*)(B + (size_t)(k0 + kk) * N + n0 + nn);
            Bs[kk][nn + 0] = bv.x; Bs[kk][nn + 1] = bv.y;
            Bs[kk][nn + 2] = bv.z; Bs[kk][nn + 3] = bv.w;
        }
        __syncthreads();
        #pragma unroll
        for (int kk = 0; kk < 16; ++kk) {
            float4 a = *(const float4*)&As[kk][ty * 4];
            float4 bb = *(const float4*)&Bs[kk][tx * 4];
            acc[0][0] += a.x * bb.x; acc[0][1] += a.x * bb.y; acc[0][2] += a.x * bb.z; acc[0][3] += a.x * bb.w;
            acc[1][0] += a.y * bb.x; acc[1][1] += a.y * bb.y; acc[1][2] += a.y * bb.z; acc[1][3] += a.y * bb.w;
            acc[2][0] += a.z * bb.x; acc[2][1] += a.z * bb.y; acc[2][2] += a.z * bb.z; acc[2][3] += a.z * bb.w;
            acc[3][0] += a.w * bb.x; acc[3][1] += a.w * bb.y; acc[3][2] += a.w * bb.z; acc[3][3] += a.w * bb.w;
        }
        __syncthreads();
    }
    float bsv[4];
    #pragma unroll
    for (int j = 0; j < 4; ++j) bsv[j] = bias[n0 + tx * 4 + j];
    #pragma unroll
    for (int i = 0; i < 4; ++i) {
        int m = m0 + ty * 4 + i;
        float vout[4];
        #pragma unroll
        for (int j = 0; j < 4; ++j) {
            float vv = acc[i][j] + bsv[j];
            if (ACT == ACT_ELU) vv = vv > 0.f ? vv : expm1f(vv);
            vout[j] = vv;
        }
        *(float4*)(C + (size_t)m * N + n0 + tx * 4) =
            make_float4(vout[0], vout[1], vout[2], vout[3]);
    }
}

// GRU combine + silu, in-place update of state
__global__ __launch_bounds__(256) void k_gru(const float* __restrict__ gi,
        const float* __restrict__ gh, float* __restrict__ stt) {
    int idx = blockIdx.x * 256 + threadIdx.x;
    int b = idx >> 8, j = idx & 255;
    size_t base = (size_t)b * (3 * HDIM);
    float gir = gi[base + j], giz = gi[base + HDIM + j], gin = gi[base + 2 * HDIM + j];
    float ghr = gh[base + j], ghz = gh[base + HDIM + j], ghn = gh[base + 2 * HDIM + j];
    float r = 1.f / (1.f + __expf(-(gir + ghr)));
    float z = 1.f / (1.f + __expf(-(giz + ghz)));
    float n = tanhf(gin + r * ghn);
    float prev = stt[idx];
    float h2 = (1.f - z) * n + z * prev;
    stt[idx] = h2 / (1.f + __expf(-h2));  // silu
}

extern "C" void kernel_launch(void* const* d_in, const int* in_sizes, int n_in,
                              void* d_out, int out_size, void* d_ws, size_t ws_size,
                              hipStream_t stream) {
    const float* x        = (const float*)d_in[0];
    const int*   batch    = (const int*)d_in[1];
    const float* W        = (const float*)d_in[2];
    const float* att_src  = (const float*)d_in[3];
    const float* att_dst  = (const float*)d_in[4];
    const float* bias_gat = (const float*)d_in[5];
    const float* W_ih     = (const float*)d_in[6];
    const float* W_hh     = (const float*)d_in[7];
    const float* b_ih     = (const float*)d_in[8];
    const float* b_hh     = (const float*)d_in[9];
    const float* W_lin    = (const float*)d_in[10];
    const float* b_lin    = (const float*)d_in[11];

    char* ws = (char*)d_ws;
    size_t off = 0;
    auto alloc = [&](size_t bytes) {
        void* p = (void*)(ws + off);
        off += (bytes + 255) & ~(size_t)255;
        return p;
    };
    float* s    = (float*)alloc((size_t)N_NODES * 4);
    int*   seg  = (int*)alloc((BGRAPH + 1) * 4);
    float* vv   = (float*)alloc(HDIM * 4);
    float* uu   = (float*)alloc(HDIM * 4);
    float* stt  = (float*)alloc((size_t)BGRAPH * HDIM * 4);
    float* aggx = (float*)alloc((size_t)BGRAPH * HDIM * 4);
    float* hbuf = (float*)alloc((size_t)BGRAPH * HDIM * 4);
    float* gi   = (float*)alloc((size_t)BGRAPH * 3 * HDIM * 4);
    float* gh   = (float*)alloc((size_t)BGRAPH * 3 * HDIM * 4);

    hipLaunchKernelGGL(k_vectors, dim3(1), dim3(HDIM), 0, stream, W, att_src, att_dst, vv, uu);
    hipLaunchKernelGGL(k_bounds, dim3(5), dim3(256), 0, stream, batch, seg);
    hipLaunchKernelGGL(k_passA, dim3(BGRAPH), dim3(256), 0, stream, x, seg, vv, s, stt);

    for (int tstep = 0; tstep < TSTEPS; ++tstep) {
        hipLaunchKernelGGL(k_iter, dim3(BGRAPH), dim3(256), 0, stream, x, seg, s, uu, stt, aggx);
        // h = elu(aggx @ W + bias_gat)
        hipLaunchKernelGGL((k_gemm<false, ACT_ELU>), dim3(BGRAPH / 64, HDIM / 64), dim3(256), 0,
                           stream, aggx, W, bias_gat, hbuf, BGRAPH, HDIM, HDIM);
        // gi = h @ W_ih^T + b_ih
        hipLaunchKernelGGL((k_gemm<true, ACT_NONE>), dim3(BGRAPH / 64, (3 * HDIM) / 64), dim3(256), 0,
                           stream, hbuf, W_ih, b_ih, gi, BGRAPH, 3 * HDIM, HDIM);
        // gh = out @ W_hh^T + b_hh
        hipLaunchKernelGGL((k_gemm<true, ACT_NONE>), dim3(BGRAPH / 64, (3 * HDIM) / 64), dim3(256), 0,
                           stream, stt, W_hh, b_hh, gh, BGRAPH, 3 * HDIM, HDIM);
        // GRU combine + silu -> stt
        hipLaunchKernelGGL(k_gru, dim3(BGRAPH * HDIM / 256), dim3(256), 0, stream, gi, gh, stt);
    }
    // final: out @ W_lin + b_lin -> d_out (f32)
    hipLaunchKernelGGL((k_gemm<false, ACT_NONE>), dim3(BGRAPH / 64, ODIM / 64), dim3(256), 0,
                       stream, stt, W_lin, b_lin, (float*)d_out, BGRAPH, ODIM, HDIM);
}

// Round 3
// 484.217 us; speedup vs baseline: 1.0787x; 1.0787x over previous
//
#include <hip/hip_runtime.h>
#include <math.h>

#define N_NODES 200000
#define BGRAPH  1024
#define HDIM    256
#define ODIM    128
#define TSTEPS  2

#define ACT_NONE 0
#define ACT_ELU  1

// K0: v = W @ att_src, u = W @ att_dst   (W row-major [H,H]; xs = x@W => v_i = sum_j W[i,j]att_src[j])
__global__ void k_vectors(const float* __restrict__ W, const float* __restrict__ att_src,
                          const float* __restrict__ att_dst, float* __restrict__ v,
                          float* __restrict__ u) {
    int i = threadIdx.x;
    float sv = 0.f, su = 0.f;
    for (int j = 0; j < HDIM; ++j) {
        float w = W[i * HDIM + j];
        sv += w * att_src[j];
        su += w * att_dst[j];
    }
    v[i] = sv; u[i] = su;
}

// K1: segment boundaries via binary search (batch sorted ascending)
__global__ void k_bounds(const int* __restrict__ batch, int* __restrict__ seg) {
    int b = blockIdx.x * blockDim.x + threadIdx.x;
    if (b > BGRAPH) return;
    if (b == BGRAPH) { seg[b] = N_NODES; return; }
    int lo = 0, hi = N_NODES;
    while (lo < hi) { int mid = (lo + hi) >> 1; if (batch[mid] < b) lo = mid + 1; else hi = mid; }
    seg[b] = lo;
}

// K2: fused pool (state_0) + s_i = x_i . v.  One block per graph, wave-per-node, 2x unrolled.
__global__ __launch_bounds__(256) void k_passA(const float* __restrict__ x,
        const int* __restrict__ seg, const float* __restrict__ v,
        float* __restrict__ s, float* __restrict__ stt) {
    int b = blockIdx.x;
    int lo = seg[b], hi = seg[b + 1];
    int t = threadIdx.x, wave = t >> 6, lane = t & 63;
    float v0 = v[4 * lane + 0], v1 = v[4 * lane + 1], v2 = v[4 * lane + 2], v3 = v[4 * lane + 3];
    float p0 = 0.f, p1 = 0.f, p2 = 0.f, p3 = 0.f;
    int i = lo + wave;
    for (; i + 4 < hi; i += 8) {
        const float4 r0 = *(const float4*)(x + (size_t)i * HDIM + 4 * lane);
        const float4 r1 = *(const float4*)(x + (size_t)(i + 4) * HDIM + 4 * lane);
        p0 += r0.x + r1.x; p1 += r0.y + r1.y; p2 += r0.z + r1.z; p3 += r0.w + r1.w;
        float pa = r0.x * v0 + r0.y * v1 + r0.z * v2 + r0.w * v3;
        float pb = r1.x * v0 + r1.y * v1 + r1.z * v2 + r1.w * v3;
        #pragma unroll
        for (int off = 32; off > 0; off >>= 1) {
            pa += __shfl_down(pa, off, 64);
            pb += __shfl_down(pb, off, 64);
        }
        if (lane == 0) { s[i] = pa; s[i + 4] = pb; }
    }
    for (; i < hi; i += 4) {
        const float4 r0 = *(const float4*)(x + (size_t)i * HDIM + 4 * lane);
        p0 += r0.x; p1 += r0.y; p2 += r0.z; p3 += r0.w;
        float pa = r0.x * v0 + r0.y * v1 + r0.z * v2 + r0.w * v3;
        #pragma unroll
        for (int off = 32; off > 0; off >>= 1) pa += __shfl_down(pa, off, 64);
        if (lane == 0) s[i] = pa;
    }
    __shared__ float comb[4][HDIM];
    comb[wave][4 * lane + 0] = p0; comb[wave][4 * lane + 1] = p1;
    comb[wave][4 * lane + 2] = p2; comb[wave][4 * lane + 3] = p3;
    __syncthreads();
    stt[(size_t)b * HDIM + t] = comb[0][t] + comb[1][t] + comb[2][t] + comb[3][t];
}

// K_iter_h: per graph b:
//   d = stt_b . u ; softmax over segment scores; aggx_b = sum_i alpha_i * x_i (kept in LDS)
//   then h_b = elu(aggx_b @ W + bias_gat)  -> hbuf   (W streamed from L2)
__global__ __launch_bounds__(256) void k_iter_h(const float* __restrict__ x,
        const int* __restrict__ seg, const float* __restrict__ s,
        const float* __restrict__ u, const float* __restrict__ stt,
        const float* __restrict__ W, const float* __restrict__ bias_gat,
        float* __restrict__ hbuf) {
    int b = blockIdx.x, t = threadIdx.x;
    int lo = seg[b], hi = seg[b + 1];
    __shared__ float red[256];
    // d = stt[b] . u
    red[t] = stt[(size_t)b * HDIM + t] * u[t];
    __syncthreads();
    for (int st = 128; st > 0; st >>= 1) { if (t < st) red[t] += red[t + st]; __syncthreads(); }
    float d = red[0];
    __syncthreads();
    // emax
    float m = -3.402823466e38f;
    for (int i = lo + t; i < hi; i += 256) {
        float e = s[i] + d; e = e > 0.f ? e : 0.01f * e;
        m = fmaxf(m, e);
    }
    red[t] = m; __syncthreads();
    for (int st = 128; st > 0; st >>= 1) { if (t < st) red[t] = fmaxf(red[t], red[t + st]); __syncthreads(); }
    float M = red[0];
    __syncthreads();
    // denom
    float sm = 0.f;
    for (int i = lo + t; i < hi; i += 256) {
        float e = s[i] + d; e = e > 0.f ? e : 0.01f * e;
        sm += __expf(e - M);
    }
    red[t] = sm; __syncthreads();
    for (int st = 128; st > 0; st >>= 1) { if (t < st) red[t] += red[t + st]; __syncthreads(); }
    float inv = (hi > lo) ? 1.0f / red[0] : 0.f;
    __syncthreads();
    // weighted aggregation, wave-per-node, 2x unrolled
    int wave = t >> 6, lane = t & 63;
    float a0 = 0.f, a1 = 0.f, a2 = 0.f, a3 = 0.f;
    int i = lo + wave;
    for (; i + 4 < hi; i += 8) {
        float e0 = s[i] + d;     e0 = e0 > 0.f ? e0 : 0.01f * e0;
        float e1 = s[i + 4] + d; e1 = e1 > 0.f ? e1 : 0.01f * e1;
        float al0 = __expf(e0 - M) * inv;
        float al1 = __expf(e1 - M) * inv;
        const float4 r0 = *(const float4*)(x + (size_t)i * HDIM + 4 * lane);
        const float4 r1 = *(const float4*)(x + (size_t)(i + 4) * HDIM + 4 * lane);
        a0 += al0 * r0.x + al1 * r1.x; a1 += al0 * r0.y + al1 * r1.y;
        a2 += al0 * r0.z + al1 * r1.z; a3 += al0 * r0.w + al1 * r1.w;
    }
    for (; i < hi; i += 4) {
        float e0 = s[i] + d; e0 = e0 > 0.f ? e0 : 0.01f * e0;
        float al0 = __expf(e0 - M) * inv;
        const float4 r0 = *(const float4*)(x + (size_t)i * HDIM + 4 * lane);
        a0 += al0 * r0.x; a1 += al0 * r0.y; a2 += al0 * r0.z; a3 += al0 * r0.w;
    }
    __shared__ float comb[4][HDIM];
    comb[wave][4 * lane + 0] = a0; comb[wave][4 * lane + 1] = a1;
    comb[wave][4 * lane + 2] = a2; comb[wave][4 * lane + 3] = a3;
    __syncthreads();
    __shared__ float ax[HDIM];
    ax[t] = comb[0][t] + comb[1][t] + comb[2][t] + comb[3][t];
    __syncthreads();
    // h_b[t] = elu( sum_i ax[i] * W[i, t] + bias_gat[t] )
    float acc = bias_gat[t];
    #pragma unroll 8
    for (int ii = 0; ii < HDIM; ++ii) acc += ax[ii] * W[(size_t)ii * HDIM + t];
    hbuf[(size_t)b * HDIM + t] = acc > 0.f ? acc : expm1f(acc);
}

// Dual GEMM (C = A*B^T + implicit bias later in k_gru): one dispatch computes
// gi (z=0: A=h, B=W_ih) and gh (z=1: A=stt, B=W_hh). 64x64 tile, 4x4 microtile, BK=16.
__global__ __launch_bounds__(256) void k_gemm2(const float* __restrict__ A0,
        const float* __restrict__ A1, const float* __restrict__ B0,
        const float* __restrict__ B1, float* __restrict__ C0, float* __restrict__ C1,
        int M, int N, int K) {
    const float* A = blockIdx.z ? A1 : A0;
    const float* B = blockIdx.z ? B1 : B0;
    float* C = blockIdx.z ? C1 : C0;
    __shared__ __align__(16) float As[16][64];
    __shared__ __align__(16) float Bs[16][64];
    int tx = threadIdx.x & 15, ty = threadIdx.x >> 4;
    int m0 = blockIdx.x * 64, n0 = blockIdx.y * 64;
    float acc[4][4] = {};
    for (int k0 = 0; k0 < K; k0 += 16) {
        {
            int r = threadIdx.x >> 2;
            int kk = (threadIdx.x & 3) << 2;
            float4 av = *(const float4*)(A + (size_t)(m0 + r) * K + k0 + kk);
            As[kk + 0][r] = av.x; As[kk + 1][r] = av.y;
            As[kk + 2][r] = av.z; As[kk + 3][r] = av.w;
            float4 bv = *(const float4*)(B + (size_t)(n0 + r) * K + k0 + kk);
            Bs[kk + 0][r] = bv.x; Bs[kk + 1][r] = bv.y;
            Bs[kk + 2][r] = bv.z; Bs[kk + 3][r] = bv.w;
        }
        __syncthreads();
        #pragma unroll
        for (int kk = 0; kk < 16; ++kk) {
            float4 a = *(const float4*)&As[kk][ty * 4];
            float4 bb = *(const float4*)&Bs[kk][tx * 4];
            acc[0][0] += a.x * bb.x; acc[0][1] += a.x * bb.y; acc[0][2] += a.x * bb.z; acc[0][3] += a.x * bb.w;
            acc[1][0] += a.y * bb.x; acc[1][1] += a.y * bb.y; acc[1][2] += a.y * bb.z; acc[1][3] += a.y * bb.w;
            acc[2][0] += a.z * bb.x; acc[2][1] += a.z * bb.y; acc[2][2] += a.z * bb.z; acc[2][3] += a.z * bb.w;
            acc[3][0] += a.w * bb.x; acc[3][1] += a.w * bb.y; acc[3][2] += a.w * bb.z; acc[3][3] += a.w * bb.w;
        }
        __syncthreads();
    }
    #pragma unroll
    for (int i = 0; i < 4; ++i) {
        int mrow = m0 + ty * 4 + i;
        *(float4*)(C + (size_t)mrow * N + n0 + tx * 4) =
            make_float4(acc[i][0], acc[i][1], acc[i][2], acc[i][3]);
    }
}

// Generic small GEMM (used for final linear): C[M,N] = A[M,K] * B[K,N] + bias
__global__ __launch_bounds__(256) void k_gemm_nn(const float* __restrict__ A,
        const float* __restrict__ B, const float* __restrict__ bias,
        float* __restrict__ C, int M, int N, int K) {
    __shared__ __align__(16) float As[16][64];
    __shared__ __align__(16) float Bs[16][64];
    int tx = threadIdx.x & 15, ty = threadIdx.x >> 4;
    int m0 = blockIdx.x * 64, n0 = blockIdx.y * 64;
    float acc[4][4] = {};
    for (int k0 = 0; k0 < K; k0 += 16) {
        {
            int r = threadIdx.x >> 2;
            int kk = (threadIdx.x & 3) << 2;
            float4 av = *(const float4*)(A + (size_t)(m0 + r) * K + k0 + kk);
            As[kk + 0][r] = av.x; As[kk + 1][r] = av.y;
            As[kk + 2][r] = av.z; As[kk + 3][r] = av.w;
        }
        {
            int kk = threadIdx.x >> 4;
            int nn = (threadIdx.x & 15) << 2;
            float4 bv = *(const float4*)(B + (size_t)(k0 + kk) * N + n0 + nn);
            Bs[kk][nn + 0] = bv.x; Bs[kk][nn + 1] = bv.y;
            Bs[kk][nn + 2] = bv.z; Bs[kk][nn + 3] = bv.w;
        }
        __syncthreads();
        #pragma unroll
        for (int kk = 0; kk < 16; ++kk) {
            float4 a = *(const float4*)&As[kk][ty * 4];
            float4 bb = *(const float4*)&Bs[kk][tx * 4];
            acc[0][0] += a.x * bb.x; acc[0][1] += a.x * bb.y; acc[0][2] += a.x * bb.z; acc[0][3] += a.x * bb.w;
            acc[1][0] += a.y * bb.x; acc[1][1] += a.y * bb.y; acc[1][2] += a.y * bb.z; acc[1][3] += a.y * bb.w;
            acc[2][0] += a.z * bb.x; acc[2][1] += a.z * bb.y; acc[2][2] += a.z * bb.z; acc[2][3] += a.z * bb.w;
            acc[3][0] += a.w * bb.x; acc[3][1] += a.w * bb.y; acc[3][2] += a.w * bb.z; acc[3][3] += a.w * bb.w;
        }
        __syncthreads();
    }
    float bsv[4];
    #pragma unroll
    for (int j = 0; j < 4; ++j) bsv[j] = bias[n0 + tx * 4 + j];
    #pragma unroll
    for (int i = 0; i < 4; ++i) {
        int mrow = m0 + ty * 4 + i;
        *(float4*)(C + (size_t)mrow * N + n0 + tx * 4) =
            make_float4(acc[i][0] + bsv[0], acc[i][1] + bsv[1],
                        acc[i][2] + bsv[2], acc[i][3] + bsv[3]);
    }
}

// GRU combine + silu, in-place state update (elementwise, no cross-row deps)
__global__ __launch_bounds__(256) void k_gru(const float* __restrict__ gi,
        const float* __restrict__ gh, const float* __restrict__ b_ih,
        const float* __restrict__ b_hh, float* __restrict__ stt) {
    int idx = blockIdx.x * 256 + threadIdx.x;
    int j = idx & 255;
    size_t base = (size_t)(idx >> 8) * (3 * HDIM);
    float gir = gi[base + j] + b_ih[j];
    float giz = gi[base + HDIM + j] + b_ih[HDIM + j];
    float gin = gi[base + 2 * HDIM + j] + b_ih[2 * HDIM + j];
    float ghr = gh[base + j] + b_hh[j];
    float ghz = gh[base + HDIM + j] + b_hh[HDIM + j];
    float ghn = gh[base + 2 * HDIM + j] + b_hh[2 * HDIM + j];
    float r = 1.f / (1.f + __expf(-(gir + ghr)));
    float z = 1.f / (1.f + __expf(-(giz + ghz)));
    float n = tanhf(gin + r * ghn);
    float prev = stt[idx];
    float h2 = (1.f - z) * n + z * prev;
    stt[idx] = h2 / (1.f + __expf(-h2));  // silu
}

extern "C" void kernel_launch(void* const* d_in, const int* in_sizes, int n_in,
                              void* d_out, int out_size, void* d_ws, size_t ws_size,
                              hipStream_t stream) {
    const float* x        = (const float*)d_in[0];
    const int*   batch    = (const int*)d_in[1];
    const float* W        = (const float*)d_in[2];
    const float* att_src  = (const float*)d_in[3];
    const float* att_dst  = (const float*)d_in[4];
    const float* bias_gat = (const float*)d_in[5];
    const float* W_ih     = (const float*)d_in[6];
    const float* W_hh     = (const float*)d_in[7];
    const float* b_ih     = (const float*)d_in[8];
    const float* b_hh     = (const float*)d_in[9];
    const float* W_lin    = (const float*)d_in[10];
    const float* b_lin    = (const float*)d_in[11];

    char* ws = (char*)d_ws;
    size_t off = 0;
    auto alloc = [&](size_t bytes) {
        void* p = (void*)(ws + off);
        off += (bytes + 255) & ~(size_t)255;
        return p;
    };
    float* s    = (float*)alloc((size_t)N_NODES * 4);
    int*   seg  = (int*)alloc((BGRAPH + 1) * 4);
    float* vv   = (float*)alloc(HDIM * 4);
    float* uu   = (float*)alloc(HDIM * 4);
    float* stt  = (float*)alloc((size_t)BGRAPH * HDIM * 4);
    float* hbuf = (float*)alloc((size_t)BGRAPH * HDIM * 4);
    float* gi   = (float*)alloc((size_t)BGRAPH * 3 * HDIM * 4);
    float* gh   = (float*)alloc((size_t)BGRAPH * 3 * HDIM * 4);

    hipLaunchKernelGGL(k_vectors, dim3(1), dim3(HDIM), 0, stream, W, att_src, att_dst, vv, uu);
    hipLaunchKernelGGL(k_bounds, dim3(5), dim3(256), 0, stream, batch, seg);
    hipLaunchKernelGGL(k_passA, dim3(BGRAPH), dim3(256), 0, stream, x, seg, vv, s, stt);

    for (int tstep = 0; tstep < TSTEPS; ++tstep) {
        // attention sweep + fused h = elu(aggx @ W + bias_gat)
        hipLaunchKernelGGL(k_iter_h, dim3(BGRAPH), dim3(256), 0, stream,
                           x, seg, s, uu, stt, W, bias_gat, hbuf);
        // gi = h @ W_ih^T ; gh = stt @ W_hh^T  (one dispatch)
        hipLaunchKernelGGL(k_gemm2, dim3(BGRAPH / 64, (3 * HDIM) / 64, 2), dim3(256), 0,
                           stream, hbuf, stt, W_ih, W_hh, gi, gh, BGRAPH, 3 * HDIM, HDIM);
        // GRU combine + silu -> stt
        hipLaunchKernelGGL(k_gru, dim3(BGRAPH * HDIM / 256), dim3(256), 0, stream,
                           gi, gh, b_ih, b_hh, stt);
    }
    // final: stt @ W_lin + b_lin -> d_out (f32)
    hipLaunchKernelGGL(k_gemm_nn, dim3(BGRAPH / 64, ODIM / 64), dim3(256), 0,
                       stream, stt, W_lin, b_lin, (float*)d_out, BGRAPH, ODIM, HDIM);
}